// Round 2
// baseline (309.079 us; speedup 1.0000x reference)
//
#include <hip/hip_runtime.h>
#include <float.h>

#define N_PART 262144
#define GRID_DIM 256
#define NUM_CELLS (GRID_DIM * GRID_DIM)
#define KSLOT 32
#define MAXNB 64

// ---------------- ws layout (all 256B-aligned) ----------------
// params     : 3 uints (min x bits, min y bits, max h bits)
// counts     : NUM_CELLS ints          (zeroed)
// cursor     : NUM_CELLS ints          (zeroed, scatter cursors)
// chunkSums  : 256 ints
// starts     : NUM_CELLS+2 ints        (CSR row starts; [NC]=[NC+1]=N)
// lin        : N ints                  (cell of each particle)
// sid        : N+64 ints               (particle ids, cell-major, unsorted)
// linS       : N ints                  (cell of rank r)
// Q          : (N+64) float4           ({x, y, id-as-float-bits, sup})

__global__ void init_params(unsigned int* params) {
    params[0] = 0x7f7fffffu;  // FLT_MAX bits (min x)
    params[1] = 0x7f7fffffu;  // FLT_MAX bits (min y)
    params[2] = 0u;           // 0.0f       (max h)
}

__global__ void reduce_kernel(const float* __restrict__ pos,
                              const float* __restrict__ sup,
                              unsigned int* params, int n) {
    __shared__ unsigned int s_minx, s_miny, s_maxh;
    if (threadIdx.x == 0) { s_minx = 0x7f7fffffu; s_miny = 0x7f7fffffu; s_maxh = 0u; }
    __syncthreads();
    const float2* pos2 = (const float2*)pos;
    float mx = FLT_MAX, my = FLT_MAX, mh = 0.0f;
    for (int i = blockIdx.x * blockDim.x + threadIdx.x; i < n;
         i += gridDim.x * blockDim.x) {
        float2 p = pos2[i];
        float h = sup[i];
        mx = fminf(mx, p.x);
        my = fminf(my, p.y);
        mh = fmaxf(mh, h);
    }
    // non-negative floats: uint compare == float compare
    atomicMin(&s_minx, __float_as_uint(mx));
    atomicMin(&s_miny, __float_as_uint(my));
    atomicMax(&s_maxh, __float_as_uint(mh));
    __syncthreads();
    if (threadIdx.x == 0) {
        atomicMin(&params[0], s_minx);
        atomicMin(&params[1], s_miny);
        atomicMax(&params[2], s_maxh);
    }
}

__global__ void bin_kernel(const float* __restrict__ pos,
                           const unsigned int* __restrict__ params,
                           int* __restrict__ counts, int* __restrict__ lin_out,
                           int n) {
    int i = blockIdx.x * blockDim.x + threadIdx.x;
    if (i >= n) return;
    float hmax  = __uint_as_float(params[2]);
    float qminx = __uint_as_float(params[0]) - hmax;
    float qminy = __uint_as_float(params[1]) - hmax;
    float2 p = ((const float2*)pos)[i];
    int cx = (int)ceilf((p.x - qminx) / hmax);
    int cy = (int)ceilf((p.y - qminy) / hmax);
    cx = min(max(cx, 0), GRID_DIM - 1);
    cy = min(max(cy, 0), GRID_DIM - 1);
    int lin = cx + GRID_DIM * cy;
    lin_out[i] = lin;
    atomicAdd(&counts[lin], 1);
}

// exclusive scan of 65536 counts: per-256-chunk local scan + chunk sums
__global__ void scan_local(const int* __restrict__ counts,
                           int* __restrict__ starts,
                           int* __restrict__ chunkSums) {
    __shared__ int sd[256];
    int t = threadIdx.x;
    int idx = blockIdx.x * 256 + t;
    int v = counts[idx];
    sd[t] = v;
    __syncthreads();
#pragma unroll
    for (int off = 1; off < 256; off <<= 1) {
        int x = (t >= off) ? sd[t - off] : 0;
        __syncthreads();
        sd[t] += x;
        __syncthreads();
    }
    starts[idx] = sd[t] - v;            // exclusive within chunk
    if (t == 255) chunkSums[blockIdx.x] = sd[t];
}

// each block sums chunkSums[0..b-1] (redundantly) and applies to its chunk
__global__ void scan_apply(int* __restrict__ starts,
                           const int* __restrict__ chunkSums, int n) {
    __shared__ int red[256];
    int t = threadIdx.x, b = blockIdx.x;
    red[t] = (t < b) ? chunkSums[t] : 0;
    __syncthreads();
#pragma unroll
    for (int s = 128; s > 0; s >>= 1) {
        if (t < s) red[t] += red[t + s];
        __syncthreads();
    }
    starts[b * 256 + t] += red[0];
    if (b == 255 && t == 0) {
        starts[NUM_CELLS]     = n;      // reference overflow row: empty
        starts[NUM_CELLS + 1] = n;
    }
}

__global__ void scatter_kernel(const int* __restrict__ lin,
                               const int* __restrict__ starts,
                               int* __restrict__ cursor,
                               int* __restrict__ sid, int n) {
    int i = blockIdx.x * blockDim.x + threadIdx.x;
    if (i >= n) return;
    int c = lin[i];
    int r = atomicAdd(&cursor[c], 1);   // arbitrary order; sorted at emit
    sid[starts[c] + r] = i;
}

// thread per cell: emit packed candidate records in ascending-id order
// (stable argsort semantics) via register-only selection-extract — no
// global-memory insertion sort (the previous version's load/store swap
// traffic), sid is read-only here.
__global__ void sortseg_kernel(const int* __restrict__ starts,
                               const int* __restrict__ sid,
                               int* __restrict__ linS,
                               float4* __restrict__ Q,
                               const float2* __restrict__ pos2,
                               const float* __restrict__ sup) {
    int c = blockIdx.x * blockDim.x + threadIdx.x;
    if (c >= NUM_CELLS) return;
    int b = starts[c], e = starts[c + 1];
    int prev = -1;
    for (int k = b; k < e; k++) {
        int best = 0x7fffffff;
        for (int s = b; s < e; s++) {
            int v = sid[s];
            best = (v > prev && v < best) ? v : best;
        }
        prev = best;
        float2 pj = pos2[best];         // bitwise copy: query numerics identical
        Q[k] = make_float4(pj.x, pj.y, __int_as_float(best), sup[best]);
        linS[k] = c;
    }
}

// One wave per RANK (cell-sorted order): consecutive waves read overlapping
// dense CSR segments -> L1/L2 hits. Wave-uniform state in SGPRs via
// readfirstlane. The reference's boundary decision RN(sqrt(s2)) <= h is an
// interval of f32 s2 values, so it collapses to ONE v_cmp_le_f32 against a
// per-wave threshold S = largest f32 < mid^2, mid = (h + nextafterf(h))/2
// (mid^2 exact in double, 50 bits; mid^2 is never a 24-bit f32 so ties are
// impossible). sqrt runs only once per stored lane in the epilogue, as
// v_sqrt_f32 * v_rcp_f32 (~3ulp, well inside the comparator tolerance).
__global__ __launch_bounds__(256) void query_kernel(
        const int* __restrict__ linS, const float4* __restrict__ Q,
        const int* __restrict__ starts,
        float* __restrict__ outN, float* __restrict__ outC,
        float* __restrict__ outR, int n) {
#pragma clang fp contract(off)
    __shared__ int   s_id[4][MAXNB];
    __shared__ float s_s2[4][MAXNB];

    int gtid = blockIdx.x * blockDim.x + threadIdx.x;
    int r    = gtid >> 6;              // rank in cell-sorted order (grid exact)
    int lane = threadIdx.x & 63;
    int wsl  = threadIdx.x >> 6;

    float4 me = Q[r];
    int   i  = __builtin_amdgcn_readfirstlane(__float_as_int(me.z));
    float px = __int_as_float(__builtin_amdgcn_readfirstlane(__float_as_int(me.x)));
    float py = __int_as_float(__builtin_amdgcn_readfirstlane(__float_as_int(me.y)));
    float h  = __int_as_float(__builtin_amdgcn_readfirstlane(__float_as_int(me.w)));
    int   L  = __builtin_amdgcn_readfirstlane(linS[r]);

    // exact f32 threshold for RN(sqrt(s2)) <= h   (h > 0, normal)
    float  hn  = __int_as_float(__float_as_int(h) + 1);     // nextafter(h, inf)
    double mid = 0.5 * ((double)h + (double)hn);
    double t2  = mid * mid;                                  // exact (50 bits)
    float  S   = (float)t2;                                  // RN
    S = ((double)S > t2) ? __int_as_float(__float_as_int(S) - 1) : S;  // RD

    // reference candidate-cell order: offs = dx + 256*dy, ij-meshgrid
    const int offs[9] = {-257, -1, 255, -256, 0, 256, -255, 1, 257};
    int cum[10], delta[9];
    cum[0] = 0;
#pragma unroll
    for (int o = 0; o < 9; o++) {
        int cell = L + offs[o];
        cell = min(max(cell, 0), NUM_CELLS);   // clip (duplicates at edges,
                                               //  exactly like the reference)
        int bb = __builtin_amdgcn_readfirstlane(starts[cell]);
        int ee = __builtin_amdgcn_readfirstlane(starts[cell + 1]);
        int cc = min(ee - bb, KSLOT);          // keep lowest-32 ids, as ref
        delta[o]  = bb - cum[o];               // idx = ll + delta[seg]
        cum[o + 1] = cum[o] + cc;
    }
    int T = cum[9];

    int total = 0;
    for (int b0 = 0; b0 < T; b0 += 64) {
        int ll = b0 + lane;
        int dsel = delta[0];
#pragma unroll
        for (int m = 1; m < 9; m++)
            dsel = (ll >= cum[m]) ? delta[m] : dsel;
        int idx = ll + dsel;                   // <= N+63: Q padded by 64
        float4 q = Q[idx];
        float dx = q.x - px;
        float dy = q.y - py;
        float s2 = dx * dx + dy * dy;          // contract(off): match XLA
        // scalar tail mask (SALU): lanes with ll >= T
        int rem = T - b0;
        unsigned long long maskT =
            (rem >= 64) ? ~0ull : ((1ull << rem) - 1ull);
        unsigned long long bal = __ballot(s2 <= S) & maskT;
        int rank = __builtin_amdgcn_mbcnt_hi(
            (unsigned)(bal >> 32),
            __builtin_amdgcn_mbcnt_lo((unsigned)bal, 0));
        int w = total + rank;
        if ((s2 <= S) && (ll < T) && (w < MAXNB)) {
            s_id[wsl][w] = __float_as_int(q.z);
            s_s2[wsl][w] = s2;
        }
        total += (int)__popcll(bal);
    }

    // wave-private LDS buffer, same-wave DS ops are ordered: no barrier.
    int stored = min(total, MAXNB);
    float rh = __builtin_amdgcn_rcpf(h);       // 1ulp; tolerance-covered
    size_t base = (size_t)i * MAXNB;           // 256B-aligned, fully written
    int   jj = s_id[wsl][lane];                // garbage beyond 'stored' is
    float ss = s_s2[wsl][lane];                //  discarded by cndmask below
    bool inb = lane < stored;
    float vN = inb ? (float)jj : -1.0f;
    float vR = inb ? __builtin_amdgcn_sqrtf(ss) * rh : 0.0f;
    outN[base + lane] = vN;
    outR[base + lane] = vR;
    if (lane == 0) outC[i] = (float)total;
}

extern "C" void kernel_launch(void* const* d_in, const int* in_sizes, int n_in,
                              void* d_out, int out_size, void* d_ws, size_t ws_size,
                              hipStream_t stream) {
    const float* pos = (const float*)d_in[0];
    const float* sup = (const float*)d_in[1];

    char* p = (char*)d_ws;
    auto alloc = [&](size_t bytes) {
        char* q = p;
        p += (bytes + 255) & ~(size_t)255;
        return q;
    };
    unsigned int* params    = (unsigned int*)alloc(256);
    int*          counts    = (int*)alloc((size_t)NUM_CELLS * 4);
    int*          cursor    = (int*)alloc((size_t)NUM_CELLS * 4);   // contiguous w/ counts
    int*          chunkSums = (int*)alloc(256 * 4);
    int*          starts    = (int*)alloc((size_t)(NUM_CELLS + 2) * 4);
    int*          lin       = (int*)alloc((size_t)N_PART * 4);
    int*          sid       = (int*)alloc((size_t)(N_PART + 64) * 4);
    int*          linS      = (int*)alloc((size_t)N_PART * 4);
    float4*       Q         = (float4*)alloc((size_t)(N_PART + 64) * 16);

    float* out  = (float*)d_out;
    float* outN = out;                              // N*64 neighbor ids (as f32)
    float* outC = out + (size_t)N_PART * MAXNB;     // N counts
    float* outR = outC + N_PART;                    // N*64 radial

    // counts+cursor are adjacent: one memset zeroes both
    hipMemsetAsync(counts, 0, (size_t)NUM_CELLS * 4 * 2, stream);
    init_params<<<1, 1, 0, stream>>>(params);
    reduce_kernel<<<256, 256, 0, stream>>>(pos, sup, params, N_PART);
    bin_kernel<<<N_PART / 256, 256, 0, stream>>>(pos, params, counts, lin, N_PART);
    scan_local<<<NUM_CELLS / 256, 256, 0, stream>>>(counts, starts, chunkSums);
    scan_apply<<<NUM_CELLS / 256, 256, 0, stream>>>(starts, chunkSums, N_PART);
    scatter_kernel<<<N_PART / 256, 256, 0, stream>>>(lin, starts, cursor, sid, N_PART);
    sortseg_kernel<<<NUM_CELLS / 256, 256, 0, stream>>>(starts, sid, linS, Q,
                                                        (const float2*)pos, sup);
    // one wave per rank: N_PART waves = N_PART*64 threads
    query_kernel<<<(N_PART * 64) / 256, 256, 0, stream>>>(
        linS, Q, starts, outN, outC, outR, N_PART);
}